// Round 4
// baseline (1160.436 us; speedup 1.0000x reference)
//
#include <hip/hip_runtime.h>

#define USER_NUM 100000
#define ITEM_NUM 50000
#define N_NODES  150000
#define EMB      64
#define NNZ      5000000
#define NELEM    (N_NODES * EMB)           // 9,600,000
#define NPART    ((N_NODES + 255) / 256)   // 586

typedef float vf4 __attribute__((ext_vector_type(4)));  // native vector: nt-builtin legal

// XCD slicing: 16-row granules so each 64B counter/stream-tail line maps to one slice
// G8=320: 2560 blocks * 4 waves = 10240 waves > 8192 capacity -> ~full occupancy
#define G8       320                        // blocks per slice
#define CHUNK    ((NNZ + G8 - 1) / G8)      // 15625
__device__ __forceinline__ int slice_of(int r) { return (r >> 4) & 7; }

// ---------- ego0 = concat(user,item) ----------
__global__ void concat_kernel(const float* __restrict__ user,
                              const float* __restrict__ item,
                              float* __restrict__ A) {
    int i = blockIdx.x * blockDim.x + threadIdx.x;
    if (i >= NELEM / 4) return;
    int base = i * 4;
    const float* src = (base < USER_NUM * EMB) ? (user + base)
                                               : (item + (base - USER_NUM * EMB));
    vf4 v = __builtin_nontemporal_load((const vf4*)src);
    __builtin_nontemporal_store(v, (vf4*)(A + base));
}

// ---------- phase 1a: per-row histogram, XCD-sliced ----------
// nt loads: keep the 20MB row stream from evicting the hot rowcnt lines in L2
__global__ void count_sliced(const int* __restrict__ row, int* __restrict__ rowcnt) {
    int slice = blockIdx.x & 7;
    int j = blockIdx.x >> 3;
    int base = j * CHUNK;
    int end = base + CHUNK; if (end > NNZ) end = NNZ;
    for (int e = base + threadIdx.x; e < end; e += 256) {
        int r = __builtin_nontemporal_load(row + e);
        if (slice_of(r) == slice) atomicAdd(&rowcnt[r], 1);
    }
}

// ---------- phase 1b: exclusive scan of rowcnt -> rowoff (3 kernels) ----------
__global__ void scan_blocks(const int* __restrict__ rowcnt, int* __restrict__ part) {
    __shared__ int sdata[256];
    int i = blockIdx.x * 256 + threadIdx.x;
    sdata[threadIdx.x] = (i < N_NODES) ? rowcnt[i] : 0;
    __syncthreads();
    for (int ofs = 128; ofs > 0; ofs >>= 1) {
        if (threadIdx.x < ofs) sdata[threadIdx.x] += sdata[threadIdx.x + ofs];
        __syncthreads();
    }
    if (threadIdx.x == 0) part[blockIdx.x] = sdata[0];
}

__global__ void scan_partials(int* __restrict__ part) {
    __shared__ int sdata[NPART];
    int t = threadIdx.x;
    for (int i = t; i < NPART; i += blockDim.x) sdata[i] = part[i];
    __syncthreads();
    if (t == 0) {
        int run = 0;
        for (int b = 0; b < NPART; ++b) { int x = sdata[b]; sdata[b] = run; run += x; }
    }
    __syncthreads();
    for (int i = t; i < NPART; i += blockDim.x) part[i] = sdata[i];
}

__global__ void scan_final(const int* __restrict__ rowcnt, const int* __restrict__ part,
                           int* __restrict__ rowoff) {
    __shared__ int sdata[256];
    int i = blockIdx.x * 256 + threadIdx.x;
    int vcur = (i < N_NODES) ? rowcnt[i] : 0;
    sdata[threadIdx.x] = vcur;
    __syncthreads();
    for (int ofs = 1; ofs < 256; ofs <<= 1) {
        int t = (threadIdx.x >= ofs) ? sdata[threadIdx.x - ofs] : 0;
        __syncthreads();
        sdata[threadIdx.x] += t;
        __syncthreads();
    }
    if (i < N_NODES) rowoff[i] = part[blockIdx.x] + sdata[threadIdx.x] - vcur;
}

// ---------- phase 1c: row-sorted scatter, XCD-sliced ----------
// mutates rowoff so that afterwards rowoff[r] == end-of-row-r
// nt loads on the row/col/vals streams: the 8B scattered sedge stores need their
// partial 64B lines to LIVE in this XCD's L2 until assembled (working set ~1.2MB/XCD);
// without nt the 55MB/pass read stream evicts them -> measured 292MB WRITE_SIZE (7x).
__global__ void scatter_sliced(const int* __restrict__ row, const int* __restrict__ col,
                               const float* __restrict__ vals,
                               int* __restrict__ rowoff, int2* __restrict__ sedge) {
    int slice = blockIdx.x & 7;
    int j = blockIdx.x >> 3;
    int base = j * CHUNK;
    int end = base + CHUNK; if (end > NNZ) end = NNZ;
    for (int e = base + threadIdx.x; e < end; e += 256) {
        int r = __builtin_nontemporal_load(row + e);
        if (slice_of(r) == slice) {
            int   c = __builtin_nontemporal_load(col + e);
            float v = __builtin_nontemporal_load(vals + e);
            int pos = atomicAdd(&rowoff[r], 1);
            int2 p; p.x = c; p.y = __float_as_int(v);
            sedge[pos] = p;   // temporal store: let L2 assemble the line
        }
    }
}

// ---------- phase 2: one wave per destination row, unroll-16 gather pipeline ----------
// MODE 1: acc = x[o] + s ; ynext = s     (x = ego0)
// MODE 2: acc += s       ; ynext = s
// MODE 3: acc = (acc + s) * 0.25
// sedge stream + output writes are nt: keep L2 capacity for the hot x[] gathers.
template <int MODE>
__global__ __launch_bounds__(256) void spmm_row_kernel(
        const int* __restrict__ rowend,
        const int2* __restrict__ sedge,
        const float* __restrict__ x,
        float* __restrict__ ynext, float* __restrict__ acc) {
    int wave = threadIdx.x >> 6;
    int lane = threadIdx.x & 63;
    int r = blockIdx.x * 4 + wave;
    if (r >= N_NODES) return;
    int start = (r == 0) ? 0 : rowend[r - 1];
    int end = rowend[r];
    float s = 0.f;
    for (int base = start; base < end; base += 64) {
        int n = end - base; if (n > 64) n = 64;
        int c = 0; float v = 0.f;
        if (lane < n) {
            long long pv = __builtin_nontemporal_load(
                (const long long*)(sedge + base + lane));
            c = (int)(unsigned int)(pv & 0xffffffffLL);
            v = __int_as_float((int)(pv >> 32));
        }
        int j = 0;
        for (; j + 16 <= n; j += 16) {
            int ck[16]; float vk[16];
#pragma unroll
            for (int k = 0; k < 16; ++k) { ck[k] = __shfl(c, j + k); vk[k] = __shfl(v, j + k); }
            float xk[16];
#pragma unroll
            for (int k = 0; k < 16; ++k) xk[k] = x[ck[k] * EMB + lane];
#pragma unroll
            for (int k = 0; k < 16; ++k) s += vk[k] * xk[k];
        }
        for (; j + 4 <= n; j += 4) {
            int   c0 = __shfl(c, j),     c1 = __shfl(c, j + 1);
            int   c2 = __shfl(c, j + 2), c3 = __shfl(c, j + 3);
            float v0 = __shfl(v, j),     v1 = __shfl(v, j + 1);
            float v2 = __shfl(v, j + 2), v3 = __shfl(v, j + 3);
            float x0 = x[c0 * EMB + lane];
            float x1 = x[c1 * EMB + lane];
            float x2 = x[c2 * EMB + lane];
            float x3 = x[c3 * EMB + lane];
            s += v0 * x0; s += v1 * x1; s += v2 * x2; s += v3 * x3;
        }
        for (; j < n; ++j) {
            int   cj = __shfl(c, j);
            float vj = __shfl(v, j);
            s += vj * x[cj * EMB + lane];
        }
    }
    int o = r * EMB + lane;
    if (MODE == 1) {
        __builtin_nontemporal_store(s, ynext + o);
        __builtin_nontemporal_store(x[o] + s, acc + o);
    } else if (MODE == 2) {
        __builtin_nontemporal_store(s, ynext + o);
        float a = __builtin_nontemporal_load(acc + o);
        __builtin_nontemporal_store(a + s, acc + o);
    } else {
        float a = __builtin_nontemporal_load(acc + o);
        __builtin_nontemporal_store((a + s) * 0.25f, acc + o);
    }
}

extern "C" void kernel_launch(void* const* d_in, const int* in_sizes, int n_in,
                              void* d_out, int out_size, void* d_ws, size_t ws_size,
                              hipStream_t stream) {
    const float* user = (const float*)d_in[0];
    const float* item = (const float*)d_in[1];
    const int*   row  = (const int*)d_in[2];
    const int*   col  = (const int*)d_in[3];
    const float* vals = (const float*)d_in[4];

    float* A      = (float*)d_ws;            // 38.4 MB (ego0 / layer-2 out)
    float* B      = A + NELEM;               // 38.4 MB
    int2*  sedge  = (int2*)(B + NELEM);      // 40 MB row-sorted packed edges
    int*   rowcnt = (int*)(sedge + NNZ);     // 0.6 MB
    int*   rowoff = rowcnt + N_NODES;        // 0.6 MB -> becomes rowend after scatter
    int*   part   = rowoff + N_NODES;        // ~2.4 KB
    float* acc    = (float*)d_out;

    const int eb = 256;
    const int cgrid = (NELEM / 4 + eb - 1) / eb;  // 9375
    const int rgrid = N_NODES / 4;                // 37500
    const int sgrid = 8 * G8;                     // 2560 sliced blocks

    hipMemsetAsync(rowcnt, 0, N_NODES * sizeof(int), stream);
    count_sliced<<<sgrid, eb, 0, stream>>>(row, rowcnt);
    scan_blocks<<<NPART, 256, 0, stream>>>(rowcnt, part);
    scan_partials<<<1, 1024, 0, stream>>>(part);
    scan_final<<<NPART, 256, 0, stream>>>(rowcnt, part, rowoff);
    scatter_sliced<<<sgrid, eb, 0, stream>>>(row, col, vals, rowoff, sedge);
    // rowoff[r] is now end-of-row-r
    concat_kernel<<<cgrid, eb, 0, stream>>>(user, item, A);

    // layer 1: ego0(A) -> B ; acc = A + B
    spmm_row_kernel<1><<<rgrid, eb, 0, stream>>>(rowoff, sedge, A, B, acc);
    // layer 2: B -> A ; acc += A
    spmm_row_kernel<2><<<rgrid, eb, 0, stream>>>(rowoff, sedge, B, A, acc);
    // layer 3: A -> (fused finalize) ; acc = (acc + s) * 0.25
    spmm_row_kernel<3><<<rgrid, eb, 0, stream>>>(rowoff, sedge, A, nullptr, acc);
}